// Round 1
// baseline (12.599 us; speedup 1.0000x reference)
//
#include <hip/hip_runtime.h>
#include <hip/hip_bf16.h>

// Shapes (fixed by the reference):
//   input:       [B=32, S=2048, H=1024] float32
//   number_mask: [B=32, S=2048] int
//   max_number:  scalar 20 -> J = 20 labels (1..20)
//   output:      [B, J, 2H] float32
#define B_DIM 32
#define S_DIM 2048
#define H_DIM 1024
#define J_DIM 20

// Kernel 1: per batch, find first/last occurrence position of each label.
__global__ void aware_idx_kernel(const int* __restrict__ mask,
                                 int* __restrict__ first_idx,
                                 int* __restrict__ last_idx) {
    const int b = blockIdx.x;
    __shared__ int sfirst[J_DIM];
    __shared__ int slast[J_DIM];
    const int t = threadIdx.x;
    if (t < J_DIM) {
        sfirst[t] = S_DIM;   // sentinel: no occurrence
        slast[t]  = -1;
    }
    __syncthreads();
    const int* m = mask + (size_t)b * S_DIM;
    for (int s = t; s < S_DIM; s += blockDim.x) {
        int v = m[s];
        if (v >= 1 && v <= J_DIM) {
            atomicMin(&sfirst[v - 1], s);
            atomicMax(&slast[v - 1], s);
        }
    }
    __syncthreads();
    if (t < J_DIM) {
        first_idx[b * J_DIM + t] = sfirst[t];
        last_idx[b * J_DIM + t]  = slast[t];
    }
}

// Kernel 2: one block per (b, j). Copy input[b, first, :] -> out[b,j,0:H],
// input[b, last, :] -> out[b,j,H:2H]; zeros if label absent.
__global__ void aware_gather_kernel(const float* __restrict__ in,
                                    const int* __restrict__ first_idx,
                                    const int* __restrict__ last_idx,
                                    float* __restrict__ out) {
    const int bj = blockIdx.x;           // b * J + j
    const int b  = bj / J_DIM;
    const int f  = first_idx[bj];
    const int l  = last_idx[bj];
    const bool exists = (f < S_DIM);

    float4* o = reinterpret_cast<float4*>(out + (size_t)bj * (2 * H_DIM));
    const int t = threadIdx.x;           // 256 threads; H/4 = 256 float4 per half

    float4 z; z.x = 0.f; z.y = 0.f; z.z = 0.f; z.w = 0.f;
    if (exists) {
        const float4* src_f = reinterpret_cast<const float4*>(
            in + ((size_t)b * S_DIM + f) * H_DIM);
        const float4* src_l = reinterpret_cast<const float4*>(
            in + ((size_t)b * S_DIM + l) * H_DIM);
        o[t]               = src_f[t];
        o[t + H_DIM / 4]   = src_l[t];
    } else {
        o[t]               = z;
        o[t + H_DIM / 4]   = z;
    }
}

extern "C" void kernel_launch(void* const* d_in, const int* in_sizes, int n_in,
                              void* d_out, int out_size, void* d_ws, size_t ws_size,
                              hipStream_t stream) {
    const float* input = (const float*)d_in[0];
    const int*   mask  = (const int*)d_in[1];
    float*       out   = (float*)d_out;

    // workspace: first[B*J], last[B*J]
    int* first_idx = (int*)d_ws;
    int* last_idx  = first_idx + B_DIM * J_DIM;

    aware_idx_kernel<<<B_DIM, 256, 0, stream>>>(mask, first_idx, last_idx);
    aware_gather_kernel<<<B_DIM * J_DIM, 256, 0, stream>>>(input, first_idx,
                                                           last_idx, out);
}

// Round 2
// 9.909 us; speedup vs baseline: 1.2715x; 1.2715x over previous
//
#include <hip/hip_runtime.h>
#include <hip/hip_bf16.h>

// Shapes (fixed by the reference):
//   input:       [B=32, S=2048, H=1024] float32
//   number_mask: [B=32, S=2048] int
//   max_number:  scalar 20 -> J = 20 labels (1..20)
//   output:      [B, J, 2H] float32
#define B_DIM 32
#define S_DIM 2048
#define H_DIM 1024
#define J_DIM 20

// One block per (b, j). Scan mask row for label j+1 (first/last position),
// then copy input[b, first, :] -> out[b,j,0:H], input[b, last, :] -> out[b,j,H:2H].
// Zeros when the label is absent (d_out is poisoned, must write explicitly).
__global__ __launch_bounds__(256) void aware_fused_kernel(
        const float* __restrict__ in,
        const int* __restrict__ mask,
        float* __restrict__ out) {
    const int bj    = blockIdx.x;        // b * J + j
    const int b     = bj / J_DIM;
    const int label = bj - b * J_DIM + 1;
    const int t     = threadIdx.x;       // 256 threads

    // --- scan mask row for first/last occurrence of `label` ---
    int lmin = S_DIM;
    int lmax = -1;
    const int* m = mask + (size_t)b * S_DIM;
    #pragma unroll
    for (int k = 0; k < S_DIM / 256; ++k) {
        int s = t + k * 256;
        int v = m[s];
        if (v == label) {
            lmin = min(lmin, s);
            lmax = max(lmax, s);
        }
    }
    // wave (64-lane) butterfly reduce
    #pragma unroll
    for (int off = 32; off > 0; off >>= 1) {
        lmin = min(lmin, __shfl_down(lmin, off, 64));
        lmax = max(lmax, __shfl_down(lmax, off, 64));
    }
    // combine 4 waves via LDS
    __shared__ int sf, sl;
    if (t == 0) { sf = S_DIM; sl = -1; }
    __syncthreads();
    if ((t & 63) == 0) {
        atomicMin(&sf, lmin);
        atomicMax(&sl, lmax);
    }
    __syncthreads();
    const int f = sf;
    const int l = sl;
    const bool exists = (f < S_DIM);

    // --- gather: H/4 = 256 float4 per half, one per thread ---
    float4* o = reinterpret_cast<float4*>(out + (size_t)bj * (2 * H_DIM));
    if (exists) {
        const float4* src_f = reinterpret_cast<const float4*>(
            in + ((size_t)b * S_DIM + f) * H_DIM);
        const float4* src_l = reinterpret_cast<const float4*>(
            in + ((size_t)b * S_DIM + l) * H_DIM);
        o[t]             = src_f[t];
        o[t + H_DIM / 4] = src_l[t];
    } else {
        float4 z; z.x = 0.f; z.y = 0.f; z.z = 0.f; z.w = 0.f;
        o[t]             = z;
        o[t + H_DIM / 4] = z;
    }
}

extern "C" void kernel_launch(void* const* d_in, const int* in_sizes, int n_in,
                              void* d_out, int out_size, void* d_ws, size_t ws_size,
                              hipStream_t stream) {
    const float* input = (const float*)d_in[0];
    const int*   mask  = (const int*)d_in[1];
    float*       out   = (float*)d_out;

    aware_fused_kernel<<<B_DIM * J_DIM, 256, 0, stream>>>(input, mask, out);
}